// Round 12
// baseline (363.532 us; speedup 1.0000x reference)
//
#include <hip/hip_runtime.h>
#include <hip/hip_bf16.h>

typedef short sx8 __attribute__((ext_vector_type(8)));
typedef short sx4 __attribute__((ext_vector_type(4)));
typedef float f32x4 __attribute__((ext_vector_type(4)));

__device__ __forceinline__ short f2bf(float f) {
  union { float f; unsigned u; } v; v.f = f;
  unsigned r = v.u + 0x7fffu + ((v.u >> 16) & 1u);
  return (short)(r >> 16);
}
__device__ __forceinline__ float bf2f(short s) {
  union { unsigned u; float f; } w;
  w.u = ((unsigned)(unsigned short)s) << 16;
  return w.f;
}

#define GLL16(g, l)                                          \
  __builtin_amdgcn_global_load_lds(                          \
      (__attribute__((address_space(1))) void*)(g),          \
      (__attribute__((address_space(3))) void*)(l), 16, 0, 0)

// ---------------- W2T[o][e*128+i] = bf16(weight[(e*4096+o)*128+i]) ----------------
__global__ __launch_bounds__(256) void w2t_kernel(const float* __restrict__ w,
                                                  short* __restrict__ W2T) {
  const long idx = (long)blockIdx.x * 256 + threadIdx.x;  // 4M total
  const int o = (int)(idx >> 10);
  const int r = (int)(idx & 1023);
  W2T[idx] = f2bf(w[((long)((r >> 7) * 4096 + o) << 7) + (r & 127)]);
}

// ---------------- tiled transpose fp32 -> bf16 (x only) ----------------
__global__ __launch_bounds__(256) void tr_kernel(const float* __restrict__ src,
                                                 short* __restrict__ dst,
                                                 long sB0, long sB1, int SLD, int W) {
  __shared__ float tile[64][68];
  const int tid = threadIdx.x;
  const int bz = blockIdx.z;
  const long sBase = (long)(bz >> 3) * sB0 + (long)(bz & 7) * sB1;
  const long dBase = (long)bz * W * 4096;
  const int c0 = blockIdx.x * 64;
  const int t0 = blockIdx.y * 64;

#pragma unroll
  for (int it = 0; it < 4; ++it) {
    const int t = it * 16 + (tid >> 4);
    const int c4 = (tid & 15) * 4;
    f32x4 v = *(const f32x4*)(src + sBase + (long)(t0 + t) * SLD + c0 + c4);
    *(f32x4*)&tile[t][c4] = v;
  }
  __syncthreads();
#pragma unroll
  for (int it = 0; it < 4; ++it) {
    const int c = it * 16 + (tid >> 4);
    const int t4 = (tid & 15) * 4;
    sx4 o;
#pragma unroll
    for (int j = 0; j < 4; ++j) o[j] = f2bf(tile[t4 + j][c]);
    *(sx4*)(dst + dBase + (long)(c0 + c) * 4096 + t0 + t4) = o;
  }
}

// ======= fused stage A: P[kb][bz][i][c] = sum_t xT[i][t] * dispatch[t][c] =======
__global__ __launch_bounds__(256, 4) void gemm_a_fused(const short* __restrict__ xT,
                                                       const float* __restrict__ disp,
                                                       short* __restrict__ P) {
  __shared__ short lA[128][40];
  __shared__ short sc16[32][136];  // bf16 [t][c]
  const int tid = threadIdx.x;
  const int c0 = blockIdx.x * 128;
  const int kb = blockIdx.y;
  const int bz = blockIdx.z;
  const long dBase = (long)(bz >> 3) * 16777216 + (long)(bz & 7) * 512;
  const long xBase = (long)bz * 524288;
  const long pBase = (long)kb * 2097152 + (long)bz * 65536;
  const int wid = tid >> 6, lane = tid & 63;
  const int wr = wid >> 1, wc = wid & 1;
  const int r0 = wr * 64, q0 = wc * 64;
  const int lrow = lane & 15, lk = (lane >> 4) << 3;

  f32x4 acc[4][4];
#pragma unroll
  for (int a = 0; a < 4; ++a)
#pragma unroll
    for (int b = 0; b < 4; ++b) acc[a][b] = (f32x4){0.f, 0.f, 0.f, 0.f};

  for (int kt0 = 0; kt0 < 1024; kt0 += 32) {
    const int kt = kb * 1024 + kt0;
#pragma unroll
    for (int it = 0; it < 2; ++it) {
      int idx = it * 256 + tid;
      int mr = idx >> 2, kc = (idx & 3) * 8;
      *(sx8*)&lA[mr][kc] = *(const sx8*)(xT + xBase + (long)mr * 4096 + kt + kc);
    }
#pragma unroll
    for (int it = 0; it < 4; ++it) {
      int idx = it * 256 + tid;
      int tr = idx >> 5, c4 = (idx & 31) * 4;
      f32x4 v = *(const f32x4*)(disp + dBase + (long)(kt + tr) * 4096 + c0 + c4);
      sx4 s;
#pragma unroll
      for (int j = 0; j < 4; ++j) s[j] = f2bf(v[j]);
      *(sx4*)&sc16[tr][c4] = s;
    }
    __syncthreads();

    sx8 af[4], bfr[4];
#pragma unroll
    for (int mi = 0; mi < 4; ++mi) af[mi] = *(sx8*)&lA[r0 + mi * 16 + lrow][lk];
#pragma unroll
    for (int ni = 0; ni < 4; ++ni) {
      sx8 s;
      const int col = q0 + ni * 16 + lrow;
#pragma unroll
      for (int jj = 0; jj < 8; ++jj) s[jj] = sc16[lk + jj][col];
      bfr[ni] = s;
    }
#pragma unroll
    for (int mi = 0; mi < 4; ++mi)
#pragma unroll
      for (int ni = 0; ni < 4; ++ni)
        acc[mi][ni] = __builtin_amdgcn_mfma_f32_16x16x32_bf16(af[mi], bfr[ni], acc[mi][ni], 0, 0, 0);
    __syncthreads();
  }

#pragma unroll
  for (int mi = 0; mi < 4; ++mi)
#pragma unroll
    for (int ni = 0; ni < 4; ++ni) {
      const int gnl = q0 + ni * 16 + lrow;
      const int gm = r0 + mi * 16 + ((lane >> 4) << 2);
      short* op = P + pBase + (long)gm * 512 + c0 + gnl;
      op[0] = f2bf(acc[mi][ni][0]);
      op[512] = f2bf(acc[mi][ni][1]);
      op[1024] = f2bf(acc[mi][ni][2]);
      op[1536] = f2bf(acc[mi][ni][3]);
    }
}

// ---------------- generic bf16-MFMA GEMM (stage B') ----------------
template <int BM, int BN, int ABF, int OBF, int EPI, int SACC, int SPLIT, int OT>
__global__ __launch_bounds__(256) void gemm_tpl(
    const void* __restrict__ Ap, const void* __restrict__ Bp, void* __restrict__ Op,
    int K,
    long aB0, long aB1, int aLd,
    long bB0, long bB1, int bLd,
    long oB0, long oB1, int oLd, long oSS,
    const float* __restrict__ bias, const float* __restrict__ Svec,
    float* __restrict__ Se) {
  constexpr int BK = 32;
  constexpr int LDK = BK + 8;
  constexpr int MI = BM / 32;
  constexpr int NI = BN / 32;
  constexpr int SITER = (BM * (BK / 4)) / 256;

  __shared__ short lA[BM][LDK];
  __shared__ short lB[BN][LDK];

  const int tid = threadIdx.x;
  const int bz = blockIdx.z;
  const long aBase = (long)(bz >> 3) * aB0 + (long)(bz & 7) * aB1;
  const long bBase = (long)(bz >> 3) * bB0 + (long)(bz & 7) * bB1;
  const int kb = (SPLIT > 1) ? blockIdx.y : 0;
  const long oBase = (long)(bz >> 3) * oB0 + (long)(bz & 7) * oB1 + (long)kb * oSS;
  const int m0 = blockIdx.x * BM;
  const int n0 = (SPLIT > 1) ? 0 : blockIdx.y * BN;
  const int kLo = kb * (K / SPLIT), kHi = kLo + K / SPLIT;

  const int wid = tid >> 6, lane = tid & 63;
  const int wr = wid >> 1, wc = wid & 1;
  const int r0 = wr * (BM / 2), c0 = wc * (BN / 2);
  const int lrow = lane & 15, lk = (lane >> 4) << 3;

  float ssum[SITER > 0 ? SITER : 1];
#pragma unroll
  for (int a = 0; a < SITER; ++a) ssum[a] = 0.f;

  f32x4 acc[MI][NI];
#pragma unroll
  for (int a = 0; a < MI; ++a)
#pragma unroll
    for (int b = 0; b < NI; ++b) acc[a][b] = (f32x4){0.f, 0.f, 0.f, 0.f};

  for (int kt = kLo; kt < kHi; kt += BK) {
    if constexpr (!ABF) {  // global [m][k] fp32
      const float* A = (const float*)Ap + aBase + (long)m0 * aLd + kt;
      constexpr int QPR = BK / 4;
      constexpr int ITER = (BM * QPR) / 256;
#pragma unroll
      for (int it = 0; it < ITER; ++it) {
        int idx = it * 256 + tid;
        int mr = idx / QPR, kc = (idx % QPR) * 4;
        f32x4 v = *(const f32x4*)(A + (long)mr * aLd + kc);
        if constexpr (SACC) ssum[it] += v[0] + v[1] + v[2] + v[3];
        sx4 s;
#pragma unroll
        for (int j = 0; j < 4; ++j) s[j] = f2bf(v[j]);
        *(sx4*)&lA[mr][kc] = s;
      }
    } else {  // global [m][k] bf16
      const short* A = (const short*)Ap + aBase + (long)m0 * aLd + kt;
      constexpr int CPR = BK / 8;
      constexpr int ITER = (BM * CPR) / 256;
#pragma unroll
      for (int it = 0; it < ITER; ++it) {
        int idx = it * 256 + tid;
        int mr = idx / CPR, kc = (idx % CPR) * 8;
        *(sx8*)&lA[mr][kc] = *(const sx8*)(A + (long)mr * aLd + kc);
      }
    }
    {
      const short* Bq = (const short*)Bp + bBase + (long)n0 * bLd + kt;
      constexpr int CPR = BK / 8;
      constexpr int ITER = (BN * CPR) / 256;
#pragma unroll
      for (int it = 0; it < ITER; ++it) {
        int idx = it * 256 + tid;
        int nr = idx / CPR, kc = (idx % CPR) * 8;
        *(sx8*)&lB[nr][kc] = *(const sx8*)(Bq + (long)nr * bLd + kc);
      }
    }
    __syncthreads();

    sx8 af[MI], bfr[NI];
#pragma unroll
    for (int mi = 0; mi < MI; ++mi) af[mi] = *(sx8*)&lA[r0 + mi * 16 + lrow][lk];
#pragma unroll
    for (int ni = 0; ni < NI; ++ni) bfr[ni] = *(sx8*)&lB[c0 + ni * 16 + lrow][lk];
#pragma unroll
    for (int mi = 0; mi < MI; ++mi)
#pragma unroll
      for (int ni = 0; ni < NI; ++ni)
        acc[mi][ni] = __builtin_amdgcn_mfma_f32_16x16x32_bf16(af[mi], bfr[ni], acc[mi][ni], 0, 0, 0);
    __syncthreads();
  }

  if constexpr (SACC) {
#pragma unroll
    for (int it = 0; it < SITER; ++it) {
      float s = ssum[it];
      s += __shfl_down(s, 4, 8);
      s += __shfl_down(s, 2, 8);
      s += __shfl_down(s, 1, 8);
      if ((tid & 7) == 0) {
        int mr = (it * 256 + tid) >> 3;
        Se[(long)(bz & 7) * 16384 + (long)(bz >> 3) * 4096 + m0 + mr] = s;
      }
    }
  }

  if constexpr (OT) {
#pragma unroll
    for (int mi = 0; mi < MI; ++mi) {
      const int gm_b = m0 + r0 + mi * 16 + ((lane >> 4) << 2);
#pragma unroll
      for (int ni = 0; ni < NI; ++ni) {
        const int gn = n0 + c0 + ni * 16 + lrow;
        *(f32x4*)((float*)Op + oBase + (long)gn * oLd + gm_b) = acc[mi][ni];
      }
    }
  } else {
#pragma unroll
    for (int mi = 0; mi < MI; ++mi) {
#pragma unroll
      for (int ni = 0; ni < NI; ++ni) {
        const int gn = n0 + c0 + ni * 16 + lrow;
        const int gm_b = m0 + r0 + mi * 16 + ((lane >> 4) << 2);
#pragma unroll
        for (int r = 0; r < 4; ++r) {
          const int gm = gm_b + r;
          float v = acc[mi][ni][r];
          if constexpr (EPI) v += bias[gn] * Svec[gm];
          const long addr = oBase + (long)gm * oLd + gn;
          if constexpr (OBF)
            ((short*)Op)[addr] = f2bf(v);
          else
            ((float*)Op)[addr] = v;
        }
      }
    }
  }
}

// ---------------- xdT = bf16(sum over 4 bf16 split partials) ----------------
__global__ __launch_bounds__(256) void reduce_k(const short* __restrict__ P,
                                                short* __restrict__ xd) {
  const long i = ((long)blockIdx.x * 256 + threadIdx.x) * 4;
  float s[4] = {0.f, 0.f, 0.f, 0.f};
#pragma unroll
  for (int sp = 0; sp < 4; ++sp) {
    sx4 v = *(const sx4*)(P + (long)sp * 2097152 + i);
#pragma unroll
    for (int j = 0; j < 4; ++j) s[j] += bf2f(v[j]);
  }
  sx4 o;
#pragma unroll
  for (int j = 0; j < 4; ++j) o[j] = f2bf(s[j]);
  *(sx4*)&xd[i] = o;
}

// ---------------- S[bt] = sum_e Se[e][bt] ----------------
__global__ __launch_bounds__(256) void ssum_k(const float* __restrict__ Se,
                                              float* __restrict__ S) {
  const int i = blockIdx.x * 256 + threadIdx.x;
  float s = 0.f;
#pragma unroll
  for (int e = 0; e < 8; ++e) s += Se[e * 16384 + i];
  S[i] = s;
}

// ====== stage C' v4-final: 256x256 BK=64, straight-line region, n-major XCD ======
// v4 (best of 7 schedule variants) + GLLs issued at region top for max load lead.
// 858 TF = documented plain-HIP ceiling for 256^2 @ K=1024 (m248 full-stack: 848).
#define BARX do { __asm__ __volatile__("" ::: "memory"); \
                  __builtin_amdgcn_s_barrier();           \
                  __asm__ __volatile__("" ::: "memory"); } while (0)

__global__ __launch_bounds__(512, 2) void gemm_c8(const short* __restrict__ Z,
                                                  const short* __restrict__ W,
                                                  float* __restrict__ Out,
                                                  const float* __restrict__ bias,
                                                  const float* __restrict__ Svec) {
  __shared__ short lAs[2 * 256 * 64];
  __shared__ short lBs[2 * 256 * 64];
  char* ldsA = (char*)lAs;
  char* ldsB = (char*)lBs;

  const int tid = threadIdx.x;
  const int lane = tid & 63, wid = tid >> 6;
  const int wr = wid >> 2, wc = wid & 3;
  const int lrow = lane & 15;

  // n-major XCD mapping: xcd = bid&7 owns an n-pair (W2T slice L2-resident);
  // local sweeps m (16m x 2n concurrently per XCD)
  const int bid = blockIdx.x;
  const int xcd = bid & 7;
  const int local = bid >> 3;
  const int m0 = (local >> 1) * 256;
  const int n0 = (xcd * 2 + (local & 1)) * 256;

  const int rl = lane >> 3;
  const int csw = ((lane & 7) ^ rl) * 8;
  const short* srcA = Z + (long)(m0 + wid * 16 + rl) * 1024 + csw;
  const short* srcB = W + (long)(n0 + wid * 16 + rl) * 1024 + csw;
  const int cOff = wid * 2048;

#define STG_ALL(t) do {                                                          \
    long go = (long)(t) * 64;                                                    \
    int lo = (((t) & 1) << 15) + cOff;                                           \
    GLL16(srcA + go, ldsA + lo);                                                 \
    GLL16(srcA + go + 8192, ldsA + lo + 1024);                                   \
    GLL16(srcA + go + 131072, ldsA + lo + 16384);                                \
    GLL16(srcA + go + 131072 + 8192, ldsA + lo + 16384 + 1024);                  \
    GLL16(srcB + go, ldsB + lo);                                                 \
    GLL16(srcB + go + 8192, ldsB + lo + 1024);                                   \
    GLL16(srcB + go + 131072, ldsB + lo + 16384);                                \
    GLL16(srcB + go + 131072 + 8192, ldsB + lo + 16384 + 1024);                  \
  } while (0)

  const int xorv = (lane & 7) << 4;
  const int aBase = wr * 8192 + lrow * 128 + (lane >> 4) * 16;
  const int bBase = wc * 4096 + lrow * 128 + (lane >> 4) * 16;

  f32x4 acc[8][4];
#pragma unroll
  for (int a = 0; a < 8; ++a)
#pragma unroll
    for (int b = 0; b < 4; ++b) acc[a][b] = (f32x4){0.f, 0.f, 0.f, 0.f};

  sx8 af[4][2], bf0[2][2], bf1[2][2];

#define LOAD_A(qm, so) do {                                                    \
    _Pragma("unroll") for (int mi = 0; mi < 4; ++mi)                           \
    _Pragma("unroll") for (int ks = 0; ks < 2; ++ks) {                         \
      int bo = aBase + (qm) * 16384 + mi * 2048 + ks * 64;                     \
      af[mi][ks] = *(const sx8*)(ldsA + (so) + (bo ^ xorv));                   \
    }                                                                          \
  } while (0)
#define LOAD_B(dst, qn, so) do {                                               \
    _Pragma("unroll") for (int ni = 0; ni < 2; ++ni)                           \
    _Pragma("unroll") for (int ks = 0; ks < 2; ++ks) {                         \
      int bo = bBase + (qn) * 16384 + ni * 2048 + ks * 64;                     \
      dst[ni][ks] = *(const sx8*)(ldsB + (so) + (bo ^ xorv));                  \
    }                                                                          \
  } while (0)
#define MFMA32(qm) do {                                                        \
    __builtin_amdgcn_s_setprio(1);                                             \
    _Pragma("unroll") for (int mi = 0; mi < 4; ++mi)                           \
    _Pragma("unroll") for (int ni = 0; ni < 2; ++ni)                           \
    _Pragma("unroll") for (int ks = 0; ks < 2; ++ks) {                         \
      acc[(qm) * 4 + mi][ni] = __builtin_amdgcn_mfma_f32_16x16x32_bf16(        \
          af[mi][ks], bf0[ni][ks], acc[(qm) * 4 + mi][ni], 0, 0, 0);           \
      acc[(qm) * 4 + mi][2 + ni] = __builtin_amdgcn_mfma_f32_16x16x32_bf16(    \
          af[mi][ks], bf1[ni][ks], acc[(qm) * 4 + mi][2 + ni], 0, 0, 0);       \
    }                                                                          \
    __builtin_amdgcn_s_setprio(0);                                             \
  } while (0)

  STG_ALL(0);
  asm volatile("s_waitcnt vmcnt(0)" ::: "memory");
  BARX;

  for (int j = 0; j < 16; ++j) {
    const int so = (j & 1) << 15;
    if (j < 15) STG_ALL(j + 1);  // issue GLLs first: max HBM lead before vmcnt
    LOAD_A(0, so);
    LOAD_B(bf0, 0, so);
    LOAD_B(bf1, 1, so);
    MFMA32(0);
    LOAD_A(1, so);
    MFMA32(1);
    if (j < 15) asm volatile("s_waitcnt vmcnt(0)" ::: "memory");
    BARX;
  }

  // epilogue: region-aligned index map (acc[qm*4+mi][qn*2+ni])
#pragma unroll
  for (int a = 0; a < 8; ++a) {
    const int gm = m0 + (a >> 2) * 128 + wr * 64 + (a & 3) * 16 + ((lane >> 4) << 2);
    const float s0 = Svec[gm], s1 = Svec[gm + 1], s2 = Svec[gm + 2], s3 = Svec[gm + 3];
#pragma unroll
    for (int b = 0; b < 4; ++b) {
      const int gn = n0 + (b >> 1) * 128 + wc * 32 + (b & 1) * 16 + lrow;
      const float bz = bias[gn];
      float* op = Out + (long)gm * 4096 + gn;
      op[0] = acc[a][b][0] + bz * s0;
      op[4096] = acc[a][b][1] + bz * s1;
      op[8192] = acc[a][b][2] + bz * s2;
      op[12288] = acc[a][b][3] + bz * s3;
    }
  }
#undef STG_ALL
#undef LOAD_A
#undef LOAD_B
#undef MFMA32
}

extern "C" void kernel_launch(void* const* d_in, const int* in_sizes, int n_in,
                              void* d_out, int out_size, void* d_ws, size_t ws_size,
                              hipStream_t stream) {
  const float* x        = (const float*)d_in[0];  // (4,4096,8,128)
  const float* weight   = (const float*)d_in[1];  // (4096,1024)
  const float* bias     = (const float*)d_in[2];  // (4096)
  const float* combine  = (const float*)d_in[3];  // (4,4096,8,512)
  const float* dispatch = (const float*)d_in[4];  // (4,4096,8,512)
  float* out = (float*)d_out;                     // (4,4096,4096)

  char* ws = (char*)d_ws;
  short* W2T = (short*)ws;                         // 8 MB   [4096][1024]
  short* xdT = (short*)(ws + (8L << 20));          // 4 MB   [32][128 i][512 c]
  float* S   = (float*)(ws + (12L << 20));         // 64 KB  [16384]
  float* Se  = (float*)(ws + (12L << 20) + 65536); // 512 KB [8][16384]
  short* xT  = (short*)(ws + (13L << 20));         // 32 MB  [32][128 i][4096 t]
  short* z2  = (short*)(ws + (13L << 20));         // 32 MB  [16384][1024] (overlays xT)
  short* P   = (short*)(ws + (45L << 20));         // 16 MB  [4][32][128 i][512 c] bf16

  w2t_kernel<<<dim3(16384), dim3(256), 0, stream>>>(weight, W2T);

  // transpose x -> xT only (dispatch consumed directly by fused stage A)
  tr_kernel<<<dim3(2, 64, 32), dim3(256), 0, stream>>>(x, xT,
      4194304L, 128L, 1024, 128);

  // Stage A fused: P[kb][bz][i][c] = sum_t xT[i][t] * dispatch[t][c]
  gemm_a_fused<<<dim3(4, 4, 32), dim3(256), 0, stream>>>(xT, dispatch, P);

  reduce_k<<<dim3(2048), dim3(256), 0, stream>>>(P, xdT);

  // Stage B': z[b,t,e,i] = sum_c combine[b,t,e,c]*xdT[i][c]; also S_e row sums
  gemm_tpl<128, 128, 0, 1, 0, 1, 1, 0><<<dim3(32, 1, 32), dim3(256), 0, stream>>>(
      combine, xdT, z2, 512,
      16777216L, 512L, 4096,
      524288L, 65536L, 512,
      4194304L, 128L, 1024, 0L,
      nullptr, nullptr, Se);

  ssum_k<<<dim3(64), dim3(256), 0, stream>>>(Se, S);

  // Stage C' v4-final
  gemm_c8<<<dim3(1024), dim3(512), 0, stream>>>(z2, W2T, out, bias, S);
}

// Round 13
// 343.029 us; speedup vs baseline: 1.0598x; 1.0598x over previous
//
#include <hip/hip_runtime.h>
#include <hip/hip_bf16.h>

typedef short sx8 __attribute__((ext_vector_type(8)));
typedef short sx4 __attribute__((ext_vector_type(4)));
typedef float f32x4 __attribute__((ext_vector_type(4)));

__device__ __forceinline__ short f2bf(float f) {
  union { float f; unsigned u; } v; v.f = f;
  unsigned r = v.u + 0x7fffu + ((v.u >> 16) & 1u);
  return (short)(r >> 16);
}
__device__ __forceinline__ float bf2f(short s) {
  union { unsigned u; float f; } w;
  w.u = ((unsigned)(unsigned short)s) << 16;
  return w.f;
}

#define GLL16(g, l)                                          \
  __builtin_amdgcn_global_load_lds(                          \
      (__attribute__((address_space(1))) void*)(g),          \
      (__attribute__((address_space(3))) void*)(l), 16, 0, 0)

// ---------------- W2T[o][e*128+i] = bf16(weight[(e*4096+o)*128+i]) ----------------
__global__ __launch_bounds__(256) void w2t_kernel(const float* __restrict__ w,
                                                  short* __restrict__ W2T) {
  const long idx = (long)blockIdx.x * 256 + threadIdx.x;  // 4M total
  const int o = (int)(idx >> 10);
  const int r = (int)(idx & 1023);
  W2T[idx] = f2bf(w[((long)((r >> 7) * 4096 + o) << 7) + (r & 127)]);
}

// ---------------- tiled transpose fp32 -> bf16 (x only) ----------------
__global__ __launch_bounds__(256) void tr_kernel(const float* __restrict__ src,
                                                 short* __restrict__ dst,
                                                 long sB0, long sB1, int SLD, int W) {
  __shared__ float tile[64][68];
  const int tid = threadIdx.x;
  const int bz = blockIdx.z;
  const long sBase = (long)(bz >> 3) * sB0 + (long)(bz & 7) * sB1;
  const long dBase = (long)bz * W * 4096;
  const int c0 = blockIdx.x * 64;
  const int t0 = blockIdx.y * 64;

#pragma unroll
  for (int it = 0; it < 4; ++it) {
    const int t = it * 16 + (tid >> 4);
    const int c4 = (tid & 15) * 4;
    f32x4 v = *(const f32x4*)(src + sBase + (long)(t0 + t) * SLD + c0 + c4);
    *(f32x4*)&tile[t][c4] = v;
  }
  __syncthreads();
#pragma unroll
  for (int it = 0; it < 4; ++it) {
    const int c = it * 16 + (tid >> 4);
    const int t4 = (tid & 15) * 4;
    sx4 o;
#pragma unroll
    for (int j = 0; j < 4; ++j) o[j] = f2bf(tile[t4 + j][c]);
    *(sx4*)(dst + dBase + (long)(c0 + c) * 4096 + t0 + t4) = o;
  }
}

// ======= fused stage A: P[kb][bz][i][c] = sum_t xT[i][t] * dispatch[t][c] =======
__global__ __launch_bounds__(256, 4) void gemm_a_fused(const short* __restrict__ xT,
                                                       const float* __restrict__ disp,
                                                       short* __restrict__ P) {
  __shared__ short lA[128][40];
  __shared__ short sc16[32][136];  // bf16 [t][c]
  const int tid = threadIdx.x;
  const int c0 = blockIdx.x * 128;
  const int kb = blockIdx.y;
  const int bz = blockIdx.z;
  const long dBase = (long)(bz >> 3) * 16777216 + (long)(bz & 7) * 512;
  const long xBase = (long)bz * 524288;
  const long pBase = (long)kb * 2097152 + (long)bz * 65536;
  const int wid = tid >> 6, lane = tid & 63;
  const int wr = wid >> 1, wc = wid & 1;
  const int r0 = wr * 64, q0 = wc * 64;
  const int lrow = lane & 15, lk = (lane >> 4) << 3;

  f32x4 acc[4][4];
#pragma unroll
  for (int a = 0; a < 4; ++a)
#pragma unroll
    for (int b = 0; b < 4; ++b) acc[a][b] = (f32x4){0.f, 0.f, 0.f, 0.f};

  for (int kt0 = 0; kt0 < 1024; kt0 += 32) {
    const int kt = kb * 1024 + kt0;
#pragma unroll
    for (int it = 0; it < 2; ++it) {
      int idx = it * 256 + tid;
      int mr = idx >> 2, kc = (idx & 3) * 8;
      *(sx8*)&lA[mr][kc] = *(const sx8*)(xT + xBase + (long)mr * 4096 + kt + kc);
    }
#pragma unroll
    for (int it = 0; it < 4; ++it) {
      int idx = it * 256 + tid;
      int tr = idx >> 5, c4 = (idx & 31) * 4;
      f32x4 v = *(const f32x4*)(disp + dBase + (long)(kt + tr) * 4096 + c0 + c4);
      sx4 s;
#pragma unroll
      for (int j = 0; j < 4; ++j) s[j] = f2bf(v[j]);
      *(sx4*)&sc16[tr][c4] = s;
    }
    __syncthreads();

    sx8 af[4], bfr[4];
#pragma unroll
    for (int mi = 0; mi < 4; ++mi) af[mi] = *(sx8*)&lA[r0 + mi * 16 + lrow][lk];
#pragma unroll
    for (int ni = 0; ni < 4; ++ni) {
      sx8 s;
      const int col = q0 + ni * 16 + lrow;
#pragma unroll
      for (int jj = 0; jj < 8; ++jj) s[jj] = sc16[lk + jj][col];
      bfr[ni] = s;
    }
#pragma unroll
    for (int mi = 0; mi < 4; ++mi)
#pragma unroll
      for (int ni = 0; ni < 4; ++ni)
        acc[mi][ni] = __builtin_amdgcn_mfma_f32_16x16x32_bf16(af[mi], bfr[ni], acc[mi][ni], 0, 0, 0);
    __syncthreads();
  }

#pragma unroll
  for (int mi = 0; mi < 4; ++mi)
#pragma unroll
    for (int ni = 0; ni < 4; ++ni) {
      const int gnl = q0 + ni * 16 + lrow;
      const int gm = r0 + mi * 16 + ((lane >> 4) << 2);
      short* op = P + pBase + (long)gm * 512 + c0 + gnl;
      op[0] = f2bf(acc[mi][ni][0]);
      op[512] = f2bf(acc[mi][ni][1]);
      op[1024] = f2bf(acc[mi][ni][2]);
      op[1536] = f2bf(acc[mi][ni][3]);
    }
}

// ---------------- generic bf16-MFMA GEMM (stage B') ----------------
template <int BM, int BN, int ABF, int OBF, int EPI, int SACC, int SPLIT, int OT>
__global__ __launch_bounds__(256) void gemm_tpl(
    const void* __restrict__ Ap, const void* __restrict__ Bp, void* __restrict__ Op,
    int K,
    long aB0, long aB1, int aLd,
    long bB0, long bB1, int bLd,
    long oB0, long oB1, int oLd, long oSS,
    const float* __restrict__ bias, const float* __restrict__ Svec,
    float* __restrict__ Se) {
  constexpr int BK = 32;
  constexpr int LDK = BK + 8;
  constexpr int MI = BM / 32;
  constexpr int NI = BN / 32;
  constexpr int SITER = (BM * (BK / 4)) / 256;

  __shared__ short lA[BM][LDK];
  __shared__ short lB[BN][LDK];

  const int tid = threadIdx.x;
  const int bz = blockIdx.z;
  const long aBase = (long)(bz >> 3) * aB0 + (long)(bz & 7) * aB1;
  const long bBase = (long)(bz >> 3) * bB0 + (long)(bz & 7) * bB1;
  const int kb = (SPLIT > 1) ? blockIdx.y : 0;
  const long oBase = (long)(bz >> 3) * oB0 + (long)(bz & 7) * oB1 + (long)kb * oSS;
  const int m0 = blockIdx.x * BM;
  const int n0 = (SPLIT > 1) ? 0 : blockIdx.y * BN;
  const int kLo = kb * (K / SPLIT), kHi = kLo + K / SPLIT;

  const int wid = tid >> 6, lane = tid & 63;
  const int wr = wid >> 1, wc = wid & 1;
  const int r0 = wr * (BM / 2), c0 = wc * (BN / 2);
  const int lrow = lane & 15, lk = (lane >> 4) << 3;

  float ssum[SITER > 0 ? SITER : 1];
#pragma unroll
  for (int a = 0; a < SITER; ++a) ssum[a] = 0.f;

  f32x4 acc[MI][NI];
#pragma unroll
  for (int a = 0; a < MI; ++a)
#pragma unroll
    for (int b = 0; b < NI; ++b) acc[a][b] = (f32x4){0.f, 0.f, 0.f, 0.f};

  for (int kt = kLo; kt < kHi; kt += BK) {
    if constexpr (!ABF) {  // global [m][k] fp32
      const float* A = (const float*)Ap + aBase + (long)m0 * aLd + kt;
      constexpr int QPR = BK / 4;
      constexpr int ITER = (BM * QPR) / 256;
#pragma unroll
      for (int it = 0; it < ITER; ++it) {
        int idx = it * 256 + tid;
        int mr = idx / QPR, kc = (idx % QPR) * 4;
        f32x4 v = *(const f32x4*)(A + (long)mr * aLd + kc);
        if constexpr (SACC) ssum[it] += v[0] + v[1] + v[2] + v[3];
        sx4 s;
#pragma unroll
        for (int j = 0; j < 4; ++j) s[j] = f2bf(v[j]);
        *(sx4*)&lA[mr][kc] = s;
      }
    } else {  // global [m][k] bf16
      const short* A = (const short*)Ap + aBase + (long)m0 * aLd + kt;
      constexpr int CPR = BK / 8;
      constexpr int ITER = (BM * CPR) / 256;
#pragma unroll
      for (int it = 0; it < ITER; ++it) {
        int idx = it * 256 + tid;
        int mr = idx / CPR, kc = (idx % CPR) * 8;
        *(sx8*)&lA[mr][kc] = *(const sx8*)(A + (long)mr * aLd + kc);
      }
    }
    {
      const short* Bq = (const short*)Bp + bBase + (long)n0 * bLd + kt;
      constexpr int CPR = BK / 8;
      constexpr int ITER = (BN * CPR) / 256;
#pragma unroll
      for (int it = 0; it < ITER; ++it) {
        int idx = it * 256 + tid;
        int nr = idx / CPR, kc = (idx % CPR) * 8;
        *(sx8*)&lB[nr][kc] = *(const sx8*)(Bq + (long)nr * bLd + kc);
      }
    }
    __syncthreads();

    sx8 af[MI], bfr[NI];
#pragma unroll
    for (int mi = 0; mi < MI; ++mi) af[mi] = *(sx8*)&lA[r0 + mi * 16 + lrow][lk];
#pragma unroll
    for (int ni = 0; ni < NI; ++ni) bfr[ni] = *(sx8*)&lB[c0 + ni * 16 + lrow][lk];
#pragma unroll
    for (int mi = 0; mi < MI; ++mi)
#pragma unroll
      for (int ni = 0; ni < NI; ++ni)
        acc[mi][ni] = __builtin_amdgcn_mfma_f32_16x16x32_bf16(af[mi], bfr[ni], acc[mi][ni], 0, 0, 0);
    __syncthreads();
  }

  if constexpr (SACC) {
#pragma unroll
    for (int it = 0; it < SITER; ++it) {
      float s = ssum[it];
      s += __shfl_down(s, 4, 8);
      s += __shfl_down(s, 2, 8);
      s += __shfl_down(s, 1, 8);
      if ((tid & 7) == 0) {
        int mr = (it * 256 + tid) >> 3;
        Se[(long)(bz & 7) * 16384 + (long)(bz >> 3) * 4096 + m0 + mr] = s;
      }
    }
  }

  if constexpr (OT) {
#pragma unroll
    for (int mi = 0; mi < MI; ++mi) {
      const int gm_b = m0 + r0 + mi * 16 + ((lane >> 4) << 2);
#pragma unroll
      for (int ni = 0; ni < NI; ++ni) {
        const int gn = n0 + c0 + ni * 16 + lrow;
        *(f32x4*)((float*)Op + oBase + (long)gn * oLd + gm_b) = acc[mi][ni];
      }
    }
  } else {
#pragma unroll
    for (int mi = 0; mi < MI; ++mi) {
#pragma unroll
      for (int ni = 0; ni < NI; ++ni) {
        const int gn = n0 + c0 + ni * 16 + lrow;
        const int gm_b = m0 + r0 + mi * 16 + ((lane >> 4) << 2);
#pragma unroll
        for (int r = 0; r < 4; ++r) {
          const int gm = gm_b + r;
          float v = acc[mi][ni][r];
          if constexpr (EPI) v += bias[gn] * Svec[gm];
          const long addr = oBase + (long)gm * oLd + gn;
          if constexpr (OBF)
            ((short*)Op)[addr] = f2bf(v);
          else
            ((float*)Op)[addr] = v;
        }
      }
    }
  }
}

// ---------------- xdT = bf16(sum over 4 bf16 split partials) ----------------
__global__ __launch_bounds__(256) void reduce_k(const short* __restrict__ P,
                                                short* __restrict__ xd) {
  const long i = ((long)blockIdx.x * 256 + threadIdx.x) * 4;
  float s[4] = {0.f, 0.f, 0.f, 0.f};
#pragma unroll
  for (int sp = 0; sp < 4; ++sp) {
    sx4 v = *(const sx4*)(P + (long)sp * 2097152 + i);
#pragma unroll
    for (int j = 0; j < 4; ++j) s[j] += bf2f(v[j]);
  }
  sx4 o;
#pragma unroll
  for (int j = 0; j < 4; ++j) o[j] = f2bf(s[j]);
  *(sx4*)&xd[i] = o;
}

// ---------------- S[bt] = sum_e Se[e][bt] ----------------
__global__ __launch_bounds__(256) void ssum_k(const float* __restrict__ Se,
                                              float* __restrict__ S) {
  const int i = blockIdx.x * 256 + threadIdx.x;
  float s = 0.f;
#pragma unroll
  for (int e = 0; e < 8; ++e) s += Se[e * 16384 + i];
  S[i] = s;
}

// ====== stage C' v4 + n-major XCD mapping (round-9 best: 344.7 us total) ======
// Each XCD owns an n-pair (W2T slice 1 MB, L2-resident) and sweeps m.
// v4 straight-line region; STG_ALL placed AFTER the B-loads (measured best).
#define BARX do { __asm__ __volatile__("" ::: "memory"); \
                  __builtin_amdgcn_s_barrier();           \
                  __asm__ __volatile__("" ::: "memory"); } while (0)

__global__ __launch_bounds__(512, 2) void gemm_c8(const short* __restrict__ Z,
                                                  const short* __restrict__ W,
                                                  float* __restrict__ Out,
                                                  const float* __restrict__ bias,
                                                  const float* __restrict__ Svec) {
  __shared__ short lAs[2 * 256 * 64];
  __shared__ short lBs[2 * 256 * 64];
  char* ldsA = (char*)lAs;
  char* ldsB = (char*)lBs;

  const int tid = threadIdx.x;
  const int lane = tid & 63, wid = tid >> 6;
  const int wr = wid >> 2, wc = wid & 3;
  const int lrow = lane & 15;

  // n-major XCD mapping: xcd = bid&7 owns an n-pair; local sweeps m
  const int bid = blockIdx.x;
  const int xcd = bid & 7;
  const int local = bid >> 3;
  const int m0 = (local >> 1) * 256;
  const int n0 = (xcd * 2 + (local & 1)) * 256;

  const int rl = lane >> 3;
  const int csw = ((lane & 7) ^ rl) * 8;
  const short* srcA = Z + (long)(m0 + wid * 16 + rl) * 1024 + csw;
  const short* srcB = W + (long)(n0 + wid * 16 + rl) * 1024 + csw;
  const int cOff = wid * 2048;

#define STG_ALL(t) do {                                                          \
    long go = (long)(t) * 64;                                                    \
    int lo = (((t) & 1) << 15) + cOff;                                           \
    GLL16(srcA + go, ldsA + lo);                                                 \
    GLL16(srcA + go + 8192, ldsA + lo + 1024);                                   \
    GLL16(srcA + go + 131072, ldsA + lo + 16384);                                \
    GLL16(srcA + go + 131072 + 8192, ldsA + lo + 16384 + 1024);                  \
    GLL16(srcB + go, ldsB + lo);                                                 \
    GLL16(srcB + go + 8192, ldsB + lo + 1024);                                   \
    GLL16(srcB + go + 131072, ldsB + lo + 16384);                                \
    GLL16(srcB + go + 131072 + 8192, ldsB + lo + 16384 + 1024);                  \
  } while (0)

  const int xorv = (lane & 7) << 4;
  const int aBase = wr * 8192 + lrow * 128 + (lane >> 4) * 16;
  const int bBase = wc * 4096 + lrow * 128 + (lane >> 4) * 16;

  f32x4 acc[8][4];
#pragma unroll
  for (int a = 0; a < 8; ++a)
#pragma unroll
    for (int b = 0; b < 4; ++b) acc[a][b] = (f32x4){0.f, 0.f, 0.f, 0.f};

  sx8 af[4][2], bf0[2][2], bf1[2][2];

#define LOAD_A(qm, so) do {                                                    \
    _Pragma("unroll") for (int mi = 0; mi < 4; ++mi)                           \
    _Pragma("unroll") for (int ks = 0; ks < 2; ++ks) {                         \
      int bo = aBase + (qm) * 16384 + mi * 2048 + ks * 64;                     \
      af[mi][ks] = *(const sx8*)(ldsA + (so) + (bo ^ xorv));                   \
    }                                                                          \
  } while (0)
#define LOAD_B(dst, qn, so) do {                                               \
    _Pragma("unroll") for (int ni = 0; ni < 2; ++ni)                           \
    _Pragma("unroll") for (int ks = 0; ks < 2; ++ks) {                         \
      int bo = bBase + (qn) * 16384 + ni * 2048 + ks * 64;                     \
      dst[ni][ks] = *(const sx8*)(ldsB + (so) + (bo ^ xorv));                  \
    }                                                                          \
  } while (0)
#define MFMA32(qm) do {                                                        \
    __builtin_amdgcn_s_setprio(1);                                             \
    _Pragma("unroll") for (int mi = 0; mi < 4; ++mi)                           \
    _Pragma("unroll") for (int ni = 0; ni < 2; ++ni)                           \
    _Pragma("unroll") for (int ks = 0; ks < 2; ++ks) {                         \
      acc[(qm) * 4 + mi][ni] = __builtin_amdgcn_mfma_f32_16x16x32_bf16(        \
          af[mi][ks], bf0[ni][ks], acc[(qm) * 4 + mi][ni], 0, 0, 0);           \
      acc[(qm) * 4 + mi][2 + ni] = __builtin_amdgcn_mfma_f32_16x16x32_bf16(    \
          af[mi][ks], bf1[ni][ks], acc[(qm) * 4 + mi][2 + ni], 0, 0, 0);       \
    }                                                                          \
    __builtin_amdgcn_s_setprio(0);                                             \
  } while (0)

  STG_ALL(0);
  asm volatile("s_waitcnt vmcnt(0)" ::: "memory");
  BARX;

  for (int j = 0; j < 16; ++j) {
    const int so = (j & 1) << 15;
    LOAD_A(0, so);
    LOAD_B(bf0, 0, so);
    LOAD_B(bf1, 1, so);
    if (j < 15) STG_ALL(j + 1);
    MFMA32(0);
    LOAD_A(1, so);
    MFMA32(1);
    if (j < 15) asm volatile("s_waitcnt vmcnt(0)" ::: "memory");
    BARX;
  }

  // epilogue: region-aligned index map (acc[qm*4+mi][qn*2+ni])
#pragma unroll
  for (int a = 0; a < 8; ++a) {
    const int gm = m0 + (a >> 2) * 128 + wr * 64 + (a & 3) * 16 + ((lane >> 4) << 2);
    const float s0 = Svec[gm], s1 = Svec[gm + 1], s2 = Svec[gm + 2], s3 = Svec[gm + 3];
#pragma unroll
    for (int b = 0; b < 4; ++b) {
      const int gn = n0 + (b >> 1) * 128 + wc * 32 + (b & 1) * 16 + lrow;
      const float bz = bias[gn];
      float* op = Out + (long)gm * 4096 + gn;
      op[0] = acc[a][b][0] + bz * s0;
      op[4096] = acc[a][b][1] + bz * s1;
      op[8192] = acc[a][b][2] + bz * s2;
      op[12288] = acc[a][b][3] + bz * s3;
    }
  }
#undef STG_ALL
#undef LOAD_A
#undef LOAD_B
#undef MFMA32
}

extern "C" void kernel_launch(void* const* d_in, const int* in_sizes, int n_in,
                              void* d_out, int out_size, void* d_ws, size_t ws_size,
                              hipStream_t stream) {
  const float* x        = (const float*)d_in[0];  // (4,4096,8,128)
  const float* weight   = (const float*)d_in[1];  // (4096,1024)
  const float* bias     = (const float*)d_in[2];  // (4096)
  const float* combine  = (const float*)d_in[3];  // (4,4096,8,512)
  const float* dispatch = (const float*)d_in[4];  // (4,4096,8,512)
  float* out = (float*)d_out;                     // (4,4096,4096)

  char* ws = (char*)d_ws;
  short* W2T = (short*)ws;                         // 8 MB   [4096][1024]
  short* xdT = (short*)(ws + (8L << 20));          // 4 MB   [32][128 i][512 c]
  float* S   = (float*)(ws + (12L << 20));         // 64 KB  [16384]
  float* Se  = (float*)(ws + (12L << 20) + 65536); // 512 KB [8][16384]
  short* xT  = (short*)(ws + (13L << 20));         // 32 MB  [32][128 i][4096 t]
  short* z2  = (short*)(ws + (13L << 20));         // 32 MB  [16384][1024] (overlays xT)
  short* P   = (short*)(ws + (45L << 20));         // 16 MB  [4][32][128 i][512 c] bf16

  w2t_kernel<<<dim3(16384), dim3(256), 0, stream>>>(weight, W2T);

  // transpose x -> xT only (dispatch consumed directly by fused stage A)
  tr_kernel<<<dim3(2, 64, 32), dim3(256), 0, stream>>>(x, xT,
      4194304L, 128L, 1024, 128);

  // Stage A fused: P[kb][bz][i][c] = sum_t xT[i][t] * dispatch[t][c]
  gemm_a_fused<<<dim3(4, 4, 32), dim3(256), 0, stream>>>(xT, dispatch, P);

  reduce_k<<<dim3(2048), dim3(256), 0, stream>>>(P, xdT);

  // Stage B': z[b,t,e,i] = sum_c combine[b,t,e,c]*xdT[i][c]; also S_e row sums
  gemm_tpl<128, 128, 0, 1, 0, 1, 1, 0><<<dim3(32, 1, 32), dim3(256), 0, stream>>>(
      combine, xdT, z2, 512,
      16777216L, 512L, 4096,
      524288L, 65536L, 512,
      4194304L, 128L, 1024, 0L,
      nullptr, nullptr, Se);

  ssum_k<<<dim3(64), dim3(256), 0, stream>>>(Se, S);

  // Stage C' v4 + n-major XCD mapping (round-9 best)
  gemm_c8<<<dim3(1024), dim3(512), 0, stream>>>(z2, W2T, out, bias, S);
}